// Round 1
// baseline (294.316 us; speedup 1.0000x reference)
//
#include <hip/hip_runtime.h>
#include <math.h>

// MemoryBuffer: B=32, KD=VD=512, M=2048.
// Shift-matrix matmul is algebraically eliminated:
//   scores[b,0]   = dot(key_in[b], x[b])
//   scores[b,m]   = dot(key_mem[b,:,m-1], x[b])       (m >= 1)
//   out[b,v]      = w0*value_in[b,v] + sum_c value_mem[b,v,c] * wl[c]
//   where wl[c] = softmax_weight[c+1], wl[M-1] = 0.
// Pure HBM-bound: ~260 MiB traffic -> ~42 us floor at 6.3 TB/s.

#define B_   32
#define KD_  512
#define VD_  512
#define M_   2048
#define FCH  8            // f-chunks in k_scores (occupancy)
#define FPC  (KD_ / FCH)  // 64 f per chunk
#define COLS_PER_BLK 1024 // 256 threads x float4
#define MCH  (M_ / COLS_PER_BLK) // 2

// ------------------------------------------------------------------
// Kernel 1: partial[fc][b][c] = dot(key_mem[b, fc*FPC:(fc+1)*FPC, c], x-chunk)
// Grid: (MCH*FCH, B). Coalesced float4 along M (16B/lane).
__global__ __launch_bounds__(256) void k_scores(
    const float* __restrict__ key_mem,
    const float* __restrict__ x,
    float* __restrict__ partial)
{
    const int b   = blockIdx.y;
    const int mc  = blockIdx.x & (MCH - 1);
    const int fc  = blockIdx.x >> 1;
    const int tid = threadIdx.x;

    __shared__ float xs[FPC];
    if (tid < FPC) xs[tid] = x[b * KD_ + fc * FPC + tid];
    __syncthreads();

    const int c0 = mc * COLS_PER_BLK + tid * 4;
    const float* kp = key_mem + ((size_t)(b * KD_ + fc * FPC)) * M_ + c0;

    float4 acc = {0.f, 0.f, 0.f, 0.f};
    #pragma unroll 4
    for (int f = 0; f < FPC; ++f) {
        const float4 kk = *(const float4*)kp;
        const float xv = xs[f];
        acc.x += kk.x * xv; acc.y += kk.y * xv;
        acc.z += kk.z * xv; acc.w += kk.w * xv;
        kp += M_;
    }
    float* pp = partial + ((size_t)fc * B_ + b) * M_ + c0;
    *(float4*)pp = acc;
}

// ------------------------------------------------------------------
// Kernel 2: per-b softmax. Sums the FCH partials, computes s0 = key_in.x,
// writes SHIFTED weights wl[b][c] = w[c+1] (wl[M-1]=0) and w0[b].
__global__ __launch_bounds__(256) void k_softmax(
    const float* __restrict__ partial,
    const float* __restrict__ x,
    const float* __restrict__ key_in,
    float* __restrict__ wl,
    float* __restrict__ w0)
{
    const int b    = blockIdx.x;
    const int tid  = threadIdx.x;
    const int wave = tid >> 6, lane = tid & 63;
    __shared__ float red[4];

    // s0 = dot(key_in[b], x[b])
    float p = 0.f;
    for (int f = tid; f < KD_; f += 256) p += key_in[b * KD_ + f] * x[b * KD_ + f];
    for (int off = 32; off; off >>= 1) p += __shfl_down(p, off);
    if (lane == 0) red[wave] = p;
    __syncthreads();
    const float s0 = red[0] + red[1] + red[2] + red[3];

    // gather scores: m = tid + k*256
    float s[8];
    #pragma unroll
    for (int k = 0; k < 8; ++k) {
        const int m = tid + k * 256;
        if (m == 0) s[k] = s0;
        else {
            float a = 0.f;
            #pragma unroll
            for (int fc = 0; fc < FCH; ++fc)
                a += partial[((size_t)fc * B_ + b) * M_ + (m - 1)];
            s[k] = a;
        }
    }

    // block max
    float mx = s[0];
    #pragma unroll
    for (int k = 1; k < 8; ++k) mx = fmaxf(mx, s[k]);
    for (int off = 32; off; off >>= 1) mx = fmaxf(mx, __shfl_down(mx, off));
    __syncthreads();
    if (lane == 0) red[wave] = mx;
    __syncthreads();
    mx = fmaxf(fmaxf(red[0], red[1]), fmaxf(red[2], red[3]));

    // exp + block sum
    float e[8], sum = 0.f;
    #pragma unroll
    for (int k = 0; k < 8; ++k) { e[k] = expf(s[k] - mx); sum += e[k]; }
    for (int off = 32; off; off >>= 1) sum += __shfl_down(sum, off);
    __syncthreads();
    if (lane == 0) red[wave] = sum;
    __syncthreads();
    sum = red[0] + red[1] + red[2] + red[3];
    const float inv = 1.0f / sum;

    #pragma unroll
    for (int k = 0; k < 8; ++k) {
        const int m = tid + k * 256;
        const float w = e[k] * inv;
        if (m == 0) { w0[b] = w; }                       // only tid==0,k==0
        else wl[(size_t)b * M_ + (m - 1)] = w;
    }
    if (tid == 0) wl[(size_t)b * M_ + (M_ - 1)] = 0.f;
}

// ------------------------------------------------------------------
// Kernel 3: out[b,v] = w0[b]*value_in[b,v] + dot(value_mem[b,v,:], wl[b,:])
// Grid: (VD/16, B); 4 waves x 4 rows each; wave-per-row, float4 + LDS weights.
__global__ __launch_bounds__(256) void k_out(
    const float* __restrict__ value_mem,
    const float* __restrict__ value_in,
    const float* __restrict__ wl,
    const float* __restrict__ w0,
    float* __restrict__ out)
{
    const int b   = blockIdx.y;
    const int vc  = blockIdx.x;
    const int tid = threadIdx.x;
    const int wave = tid >> 6, lane = tid & 63;

    __shared__ float wls[M_];
    for (int i = tid; i < M_ / 4; i += 256)
        *(float4*)&wls[i * 4] = *(const float4*)&wl[(size_t)b * M_ + i * 4];
    __syncthreads();

    const float w0b = w0[b];
    #pragma unroll
    for (int r = 0; r < 4; ++r) {
        const int v = vc * 16 + wave * 4 + r;
        const float* vp = value_mem + ((size_t)(b * VD_ + v)) * M_;
        float4 acc = {0.f, 0.f, 0.f, 0.f};
        #pragma unroll
        for (int it = 0; it < 8; ++it) {
            const int idx = it * 256 + lane * 4;
            const float4 vv = *(const float4*)(vp + idx);
            const float4 ww = *(const float4*)&wls[idx];
            acc.x += vv.x * ww.x; acc.y += vv.y * ww.y;
            acc.z += vv.z * ww.z; acc.w += vv.w * ww.w;
        }
        float a = acc.x + acc.y + acc.z + acc.w;
        for (int off = 32; off; off >>= 1) a += __shfl_down(a, off);
        if (lane == 0) out[b * VD_ + v] = a + w0b * value_in[b * VD_ + v];
    }
}

// ------------------------------------------------------------------
extern "C" void kernel_launch(void* const* d_in, const int* in_sizes, int n_in,
                              void* d_out, int out_size, void* d_ws, size_t ws_size,
                              hipStream_t stream)
{
    const float* key_mem   = (const float*)d_in[0];
    const float* value_mem = (const float*)d_in[1];
    const float* x         = (const float*)d_in[2];
    const float* key_in    = (const float*)d_in[3];
    const float* value_in  = (const float*)d_in[4];
    // d_in[5] = II shift matrix: structure known, never read.

    float* out = (float*)d_out;

    // ws layout: partial (FCH*B*M) | wl (B*M) | w0 (B)
    float* partial = (float*)d_ws;
    float* wl      = partial + (size_t)FCH * B_ * M_;
    float* w0      = wl + (size_t)B_ * M_;

    k_scores <<<dim3(MCH * FCH, B_), 256, 0, stream>>>(key_mem, x, partial);
    k_softmax<<<dim3(B_),           256, 0, stream>>>(partial, x, key_in, wl, w0);
    k_out    <<<dim3(VD_ / 16, B_), 256, 0, stream>>>(value_mem, value_in, wl, w0, out);
}

// Round 5
// 270.958 us; speedup vs baseline: 1.0862x; 1.0862x over previous
//
#include <hip/hip_runtime.h>
#include <math.h>

// MemoryBuffer: B=32, KD=VD=512, M=2048.
// Shift-matrix matmul eliminated algebraically:
//   scores[b,0] = dot(key_in[b], x[b]); scores[b,m] = dot(key_mem[b,:,m-1], x[b])
//   out[b,v]    = w0*value_in[b,v] + dot(value_mem[b,v,:], wl[b,:])
//   with wl[c] = softmax_w[c+1], wl[M-1] = 0  (aligned full-row dot).
// HBM-bound: ~260 MiB mandatory traffic -> ~42 us floor at 6.3 TB/s.
// R4 post-mortem: k_out used idx = it*1024 + lane*4 (stride bug from R1
// restructure) -> OOB reads past value_mem end -> GPU fault -> SIGABRT.
// R5: idx = it*256 + lane*4 (64 lanes x float4 = 256 elems/iter x 8 = 2048).

#define B_   32
#define KD_  512
#define VD_  512
#define M_   2048
#define FCH  16           // f-chunks in k_scores
#define FPC  (KD_ / FCH)  // 32 rows per chunk
#define MCH  2            // 2 column-chunks of 1024

typedef float f4 __attribute__((ext_vector_type(4)));

__device__ __forceinline__ f4 ntload4(const float* p) {
    return __builtin_nontemporal_load((const f4*)p);
}

// ------------------------------------------------------------------
// Kernel 1: partial[fc][b][c] = dot over 32 f-rows. Grid (MCH*FCH, B).
// 1024 blocks -> 4 blocks/CU -> 16 waves/CU. Full unroll: 32 loads in flight.
__global__ __launch_bounds__(256) void k_scores(
    const float* __restrict__ key_mem,
    const float* __restrict__ x,
    float* __restrict__ partial)
{
    const int b   = blockIdx.y;
    const int mc  = blockIdx.x & (MCH - 1);
    const int fc  = blockIdx.x >> 1;
    const int tid = threadIdx.x;

    __shared__ float xs[FPC];
    if (tid < FPC) xs[tid] = x[b * KD_ + fc * FPC + tid];
    __syncthreads();

    const int c0 = mc * 1024 + tid * 4;   // covers 0..2047 across mc=0,1
    const float* kp = key_mem + ((size_t)(b * KD_ + fc * FPC)) * M_ + c0;

    f4 acc = {0.f, 0.f, 0.f, 0.f};
    #pragma unroll
    for (int f = 0; f < FPC; ++f) {
        const f4 kk = ntload4(kp + (size_t)f * M_);
        acc += kk * xs[f];
    }
    *(f4*)(partial + ((size_t)fc * B_ + b) * M_ + c0) = acc;
}

// ------------------------------------------------------------------
// Kernel 2: per-b softmax, 1024 threads, 2 m's/thread, 16 independent
// partial loads each (pure ILP). Writes shifted weights wl + w0.
__global__ __launch_bounds__(1024) void k_softmax(
    const float* __restrict__ partial,
    const float* __restrict__ x,
    const float* __restrict__ key_in,
    float* __restrict__ wl,
    float* __restrict__ w0)
{
    const int b    = blockIdx.x;
    const int tid  = threadIdx.x;
    const int wave = tid >> 6, lane = tid & 63;
    __shared__ float red[16];

    // sdot = dot(key_in[b], x[b])  (KD=512 < 1024 threads)
    float p = (tid < KD_) ? key_in[b * KD_ + tid] * x[b * KD_ + tid] : 0.f;
    for (int off = 32; off; off >>= 1) p += __shfl_down(p, off);
    if (lane == 0) red[wave] = p;
    __syncthreads();
    float sdot = 0.f;
    #pragma unroll
    for (int i = 0; i < 16; ++i) sdot += red[i];
    __syncthreads();

    // gather scores for m = tid, tid+1024
    float s[2];
    #pragma unroll
    for (int k = 0; k < 2; ++k) {
        const int m = tid + k * 1024;
        if (m == 0) s[k] = sdot;
        else {
            float a = 0.f;
            #pragma unroll
            for (int fcc = 0; fcc < FCH; ++fcc)
                a += partial[((size_t)fcc * B_ + b) * M_ + (m - 1)];
            s[k] = a;
        }
    }

    // block max
    float mx = fmaxf(s[0], s[1]);
    for (int off = 32; off; off >>= 1) mx = fmaxf(mx, __shfl_down(mx, off));
    if (lane == 0) red[wave] = mx;
    __syncthreads();
    mx = red[0];
    #pragma unroll
    for (int i = 1; i < 16; ++i) mx = fmaxf(mx, red[i]);
    __syncthreads();

    // exp + block sum
    float e0 = __expf(s[0] - mx), e1 = __expf(s[1] - mx);
    float sum = e0 + e1;
    for (int off = 32; off; off >>= 1) sum += __shfl_down(sum, off);
    if (lane == 0) red[wave] = sum;
    __syncthreads();
    sum = 0.f;
    #pragma unroll
    for (int i = 0; i < 16; ++i) sum += red[i];
    const float inv = 1.0f / sum;

    #pragma unroll
    for (int k = 0; k < 2; ++k) {
        const int m = tid + k * 1024;
        const float w = (k ? e1 : e0) * inv;
        if (m == 0) w0[b] = w;
        else wl[(size_t)b * M_ + (m - 1)] = w;
    }
    if (tid == 0) wl[(size_t)b * M_ + (M_ - 1)] = 0.f;
}

// ------------------------------------------------------------------
// Kernel 3: out[b,v] = w0[b]*value_in[b,v] + dot(value_mem[b,v,:], wl[b,:])
// Grid (VD/8, B) = 2048 blocks -> 8 blocks/CU -> 32 waves/CU. 2 rows/wave.
__global__ __launch_bounds__(256) void k_out(
    const float* __restrict__ value_mem,
    const float* __restrict__ value_in,
    const float* __restrict__ wl,
    const float* __restrict__ w0,
    float* __restrict__ out)
{
    const int b   = blockIdx.y;
    const int vc  = blockIdx.x;
    const int tid = threadIdx.x;
    const int wave = tid >> 6, lane = tid & 63;

    __shared__ float wls[M_];
    for (int i = tid; i < M_ / 4; i += 256)
        *(f4*)&wls[i * 4] = *(const f4*)&wl[(size_t)b * M_ + i * 4];
    __syncthreads();

    const float w0b = w0[b];
    #pragma unroll
    for (int r = 0; r < 2; ++r) {
        const int v = vc * 8 + wave * 2 + r;
        const float* vp = value_mem + ((size_t)(b * VD_ + v)) * M_;
        f4 acc = {0.f, 0.f, 0.f, 0.f};
        #pragma unroll
        for (int it = 0; it < 8; ++it) {
            const int idx = it * 256 + lane * 4;   // 64 lanes x 4 = 256/iter
            const f4 vv = ntload4(vp + idx);
            const f4 ww = *(const f4*)&wls[idx];
            acc += vv * ww;
        }
        float a = acc[0] + acc[1] + acc[2] + acc[3];
        for (int off = 32; off; off >>= 1) a += __shfl_down(a, off);
        if (lane == 0) out[b * VD_ + v] = a + w0b * value_in[b * VD_ + v];
    }
}

// ------------------------------------------------------------------
extern "C" void kernel_launch(void* const* d_in, const int* in_sizes, int n_in,
                              void* d_out, int out_size, void* d_ws, size_t ws_size,
                              hipStream_t stream)
{
    const float* key_mem   = (const float*)d_in[0];
    const float* value_mem = (const float*)d_in[1];
    const float* x         = (const float*)d_in[2];
    const float* key_in    = (const float*)d_in[3];
    const float* value_in  = (const float*)d_in[4];
    // d_in[5] = II shift matrix: structure known, never read.

    float* out = (float*)d_out;

    // ws layout: partial (FCH*B*M = 4 MiB) | wl (B*M) | w0 (B)
    float* partial = (float*)d_ws;
    float* wl      = partial + (size_t)FCH * B_ * M_;
    float* w0      = wl + (size_t)B_ * M_;

    k_scores <<<dim3(MCH * FCH, B_), 256,  0, stream>>>(key_mem, x, partial);
    k_softmax<<<dim3(B_),            1024, 0, stream>>>(partial, x, key_in, wl, w0);
    k_out    <<<dim3(VD_ / 8, B_),   256,  0, stream>>>(value_mem, value_in, wl, w0, out);
}